// Round 1
// baseline (352.693 us; speedup 1.0000x reference)
//
#include <hip/hip_runtime.h>

#define Bsz 4096
#define Tlen 512
#define IND 18
#define HD 12

__device__ __forceinline__ float sigmoid_f(float x) {
  return __builtin_amdgcn_rcpf(1.0f + __expf(-x));
}
__device__ __forceinline__ float tanh_f(float x) {
  // tanh(x) = 1 - 2/(1+exp(2x)); handles +-inf saturation correctly
  return 1.0f - 2.0f * __builtin_amdgcn_rcpf(1.0f + __expf(2.0f * x));
}
__device__ __forceinline__ void lds_fence() {
  asm volatile("s_waitcnt lgkmcnt(0)" ::: "memory");
}

// One 16-lane group per batch element (12 active lanes; lane j owns h1[j], h2[j]
// and gate rows j, 12+j, 24+j). Weights in registers; h vectors broadcast via a
// per-group LDS slot (1 ds_write + 3 ds_read_b128), wave-synchronous.
extern "C" __global__ void __launch_bounds__(256, 1) gru2_fused(
    const float* __restrict__ x,
    const float* __restrict__ wih0, const float* __restrict__ whh0,
    const float* __restrict__ bih0, const float* __restrict__ bhh0,
    const float* __restrict__ wih1, const float* __restrict__ whh1,
    const float* __restrict__ bih1, const float* __restrict__ bhh1,
    const float* __restrict__ fcw, const float* __restrict__ fcb,
    float* __restrict__ out)
{
  const int tid  = threadIdx.x;
  const int lane = tid & 15;           // position within group
  const int g    = tid >> 4;           // group within block (0..15)
  const int b    = blockIdx.x * 16 + g;
  const int j    = (lane < HD) ? lane : (HD - 1);  // clamped gate/h index

  // per-group LDS: floats [0..11] = h1, [16..27] = h2 (stride 40 floats -> no bank conflicts)
  __shared__ float4 lds4[16][10];
  float* s1 = (float*)&lds4[g][0];
  float* s2 = (float*)&lds4[g][4];

  // ---- weights into registers ----
  float wir[IND], wiz[IND], win[IND];
#pragma unroll
  for (int k = 0; k < IND; ++k) {
    wir[k] = wih0[(0 * HD + j) * IND + k];
    wiz[k] = wih0[(1 * HD + j) * IND + k];
    win[k] = wih0[(2 * HD + j) * IND + k];
  }
  float whr0[HD], whz0[HD], whn0[HD];
  float wir1[HD], wiz1[HD], win1[HD];
  float whr1[HD], whz1[HD], whn1[HD];
#pragma unroll
  for (int k = 0; k < HD; ++k) {
    whr0[k] = whh0[(0 * HD + j) * HD + k];
    whz0[k] = whh0[(1 * HD + j) * HD + k];
    whn0[k] = whh0[(2 * HD + j) * HD + k];
    wir1[k] = wih1[(0 * HD + j) * HD + k];
    wiz1[k] = wih1[(1 * HD + j) * HD + k];
    win1[k] = wih1[(2 * HD + j) * HD + k];
    whr1[k] = whh1[(0 * HD + j) * HD + k];
    whz1[k] = whh1[(1 * HD + j) * HD + k];
    whn1[k] = whh1[(2 * HD + j) * HD + k];
  }
  const float br0  = bih0[j] + bhh0[j];
  const float bz0  = bih0[HD + j] + bhh0[HD + j];
  const float bin0 = bih0[2 * HD + j];
  const float bhn0 = bhh0[2 * HD + j];
  const float br1  = bih1[j] + bhh1[j];
  const float bz1  = bih1[HD + j] + bhh1[HD + j];
  const float bin1 = bih1[2 * HD + j];
  const float bhn1 = bhh1[2 * HD + j];
  float fw[HD];
#pragma unroll
  for (int k = 0; k < HD; ++k) fw[k] = fcw[k];
  const float fb = fcb[0];

  // ---- state ----
  float hv1[HD], hv2[HD];
#pragma unroll
  for (int k = 0; k < HD; ++k) { hv1[k] = 0.0f; hv2[k] = 0.0f; }
  float h1 = 0.0f, h2 = 0.0f;

  const float2* xp2 = (const float2*)(x + (size_t)b * Tlen * IND);  // 9 float2 per step (8B-aligned)
  float* outp = out + (size_t)b * Tlen;

  float xA[IND], xB[IND];
#pragma unroll
  for (int i = 0; i < 9; ++i) { float2 v = xp2[i]; xA[2 * i] = v.x; xA[2 * i + 1] = v.y; }

#define STEP(XV, TT)                                                                     \
  do {                                                                                   \
    float ar = br0, az = bz0, ain = bin0, ahn = bhn0;                                    \
    _Pragma("unroll")                                                                    \
    for (int k = 0; k < IND; ++k) {                                                      \
      ar += XV[k] * wir[k]; az += XV[k] * wiz[k]; ain += XV[k] * win[k];                 \
    }                                                                                    \
    _Pragma("unroll")                                                                    \
    for (int k = 0; k < HD; ++k) {                                                       \
      ar += hv1[k] * whr0[k]; az += hv1[k] * whz0[k]; ahn += hv1[k] * whn0[k];           \
    }                                                                                    \
    float r = sigmoid_f(ar), z = sigmoid_f(az);                                          \
    float n = tanh_f(ain + r * ahn);                                                     \
    h1 = n + z * (h1 - n);                                                               \
    if (lane < HD) s1[lane] = h1;                                                        \
    /* layer-1 gh: independent of h1_new -> hides the LDS write->read latency */         \
    float ar1 = br1, az1 = bz1, ain1 = bin1, ahn1 = bhn1;                                \
    _Pragma("unroll")                                                                    \
    for (int k = 0; k < HD; ++k) {                                                       \
      ar1 += hv2[k] * whr1[k]; az1 += hv2[k] * whz1[k]; ahn1 += hv2[k] * whn1[k];        \
    }                                                                                    \
    lds_fence();                                                                         \
    {                                                                                    \
      float4 a0 = lds4[g][0], a1 = lds4[g][1], a2 = lds4[g][2];                          \
      hv1[0] = a0.x; hv1[1] = a0.y; hv1[2] = a0.z; hv1[3] = a0.w;                        \
      hv1[4] = a1.x; hv1[5] = a1.y; hv1[6] = a1.z; hv1[7] = a1.w;                        \
      hv1[8] = a2.x; hv1[9] = a2.y; hv1[10] = a2.z; hv1[11] = a2.w;                      \
    }                                                                                    \
    _Pragma("unroll")                                                                    \
    for (int k = 0; k < HD; ++k) {                                                       \
      ar1 += hv1[k] * wir1[k]; az1 += hv1[k] * wiz1[k]; ain1 += hv1[k] * win1[k];        \
    }                                                                                    \
    float r1 = sigmoid_f(ar1), z1 = sigmoid_f(az1);                                      \
    float n1 = tanh_f(ain1 + r1 * ahn1);                                                 \
    h2 = n1 + z1 * (h2 - n1);                                                            \
    if (lane < HD) s2[lane] = h2;                                                        \
    lds_fence();                                                                         \
    {                                                                                    \
      float4 c0 = lds4[g][4], c1 = lds4[g][5], c2 = lds4[g][6];                          \
      hv2[0] = c0.x; hv2[1] = c0.y; hv2[2] = c0.z; hv2[3] = c0.w;                        \
      hv2[4] = c1.x; hv2[5] = c1.y; hv2[6] = c1.z; hv2[7] = c1.w;                        \
      hv2[8] = c2.x; hv2[9] = c2.y; hv2[10] = c2.z; hv2[11] = c2.w;                      \
    }                                                                                    \
    float o = fb;                                                                        \
    _Pragma("unroll")                                                                    \
    for (int k = 0; k < HD; ++k) o += hv2[k] * fw[k];                                    \
    if (lane == 0) outp[TT] = o;                                                         \
  } while (0)

  for (int t = 0; t < Tlen; t += 2) {
    {  // prefetch t+1
      const float2* p = xp2 + (size_t)(t + 1) * 9;
#pragma unroll
      for (int i = 0; i < 9; ++i) { float2 v = p[i]; xB[2 * i] = v.x; xB[2 * i + 1] = v.y; }
    }
    STEP(xA, t);
    if (t + 2 < Tlen) {  // prefetch t+2
      const float2* p = xp2 + (size_t)(t + 2) * 9;
#pragma unroll
      for (int i = 0; i < 9; ++i) { float2 v = p[i]; xA[2 * i] = v.x; xA[2 * i + 1] = v.y; }
    }
    STEP(xB, t + 1);
  }
#undef STEP
}

extern "C" void kernel_launch(void* const* d_in, const int* in_sizes, int n_in,
                              void* d_out, int out_size, void* d_ws, size_t ws_size,
                              hipStream_t stream) {
  (void)in_sizes; (void)n_in; (void)d_ws; (void)ws_size; (void)out_size;
  const float* x    = (const float*)d_in[0];
  const float* wih0 = (const float*)d_in[1];
  const float* whh0 = (const float*)d_in[2];
  const float* bih0 = (const float*)d_in[3];
  const float* bhh0 = (const float*)d_in[4];
  const float* wih1 = (const float*)d_in[5];
  const float* whh1 = (const float*)d_in[6];
  const float* bih1 = (const float*)d_in[7];
  const float* bhh1 = (const float*)d_in[8];
  const float* fcw  = (const float*)d_in[9];
  const float* fcb  = (const float*)d_in[10];
  float* out = (float*)d_out;

  hipLaunchKernelGGL(gru2_fused, dim3(Bsz / 16), dim3(256), 0, stream,
                     x, wih0, whh0, bih0, bhh0, wih1, whh1, bih1, bhh1, fcw, fcb, out);
}

// Round 2
// 340.977 us; speedup vs baseline: 1.0344x; 1.0344x over previous
//
#include <hip/hip_runtime.h>

#define Bsz 4096
#define Tlen 512
#define IND 18
#define HD 12

__device__ __forceinline__ float sigmoid_f(float x) {
  return __builtin_amdgcn_rcpf(1.0f + __expf(-x));
}
__device__ __forceinline__ float tanh_f(float x) {
  // tanh(x) = 1 - 2/(1+exp(2x)); saturates correctly at +-inf
  return 1.0f - 2.0f * __builtin_amdgcn_rcpf(1.0f + __expf(2.0f * x));
}

// 32 lanes per batch element: lane = (j = tid&15 [12 active], hl = (tid>>4)&1).
// Every dot product is k-split between lane pairs (l, l^16), combined with one
// ds_swizzle (__shfl_xor 16). 4096*32 threads = 2048 waves = 2 waves/SIMD.
// LDS broadcasts (h1, h2) are issued early and consumed late; FC output of
// step t is deferred into step t+1 so no read ever fences right after a write.
extern "C" __global__ void __launch_bounds__(256, 2) gru2_fused32(
    const float* __restrict__ x,
    const float* __restrict__ wih0, const float* __restrict__ whh0,
    const float* __restrict__ bih0, const float* __restrict__ bhh0,
    const float* __restrict__ wih1, const float* __restrict__ whh1,
    const float* __restrict__ bih1, const float* __restrict__ bhh1,
    const float* __restrict__ fcw, const float* __restrict__ fcb,
    float* __restrict__ out)
{
  const int tid    = threadIdx.x;
  const int lane15 = tid & 15;
  const int hl     = (tid >> 4) & 1;          // k-half
  const int g      = tid >> 5;                // batch within block (0..7)
  const int b      = blockIdx.x * 8 + g;
  const int j      = (lane15 < HD) ? lane15 : (HD - 1);
  const bool act   = (lane15 < HD);

  // per-group LDS: [0..11]=h1, [20..31]=h2; stride 40 floats keeps writes <=2-way
  __shared__ float lds[8][40];
  float* sh1 = &lds[g][0];
  float* sh2 = &lds[g][20];

  // ---- per-lane weight slices (k-split by hl) ----
  float wrx[9], wzx[9], wnx[9];          // layer0 ih, rows j / 12+j / 24+j, k = hl*9+i
#pragma unroll
  for (int i = 0; i < 9; ++i) {
    wrx[i] = wih0[(0 * HD + j) * IND + hl * 9 + i];
    wzx[i] = wih0[(1 * HD + j) * IND + hl * 9 + i];
    wnx[i] = wih0[(2 * HD + j) * IND + hl * 9 + i];
  }
  float wrh[6], wzh[6], wnh[6];          // layer0 hh, k = hl*6+i
  float wr1i[6], wz1i[6], wn1i[6];       // layer1 ih
  float wr1h[6], wz1h[6], wn1h[6];       // layer1 hh
  float fw6[6];
#pragma unroll
  for (int i = 0; i < 6; ++i) {
    int k = hl * 6 + i;
    wrh[i]  = whh0[(0 * HD + j) * HD + k];
    wzh[i]  = whh0[(1 * HD + j) * HD + k];
    wnh[i]  = whh0[(2 * HD + j) * HD + k];
    wr1i[i] = wih1[(0 * HD + j) * HD + k];
    wz1i[i] = wih1[(1 * HD + j) * HD + k];
    wn1i[i] = wih1[(2 * HD + j) * HD + k];
    wr1h[i] = whh1[(0 * HD + j) * HD + k];
    wz1h[i] = whh1[(1 * HD + j) * HD + k];
    wn1h[i] = whh1[(2 * HD + j) * HD + k];
    fw6[i]  = fcw[k];
  }
  // biases folded into half-0 partials only
  const float rb0  = hl ? 0.f : (bih0[j] + bhh0[j]);
  const float zb0  = hl ? 0.f : (bih0[HD + j] + bhh0[HD + j]);
  const float inb0 = hl ? 0.f : bih0[2 * HD + j];
  const float hnb0 = hl ? 0.f : bhh0[2 * HD + j];
  const float rb1  = hl ? 0.f : (bih1[j] + bhh1[j]);
  const float zb1  = hl ? 0.f : (bih1[HD + j] + bhh1[HD + j]);
  const float inb1 = hl ? 0.f : bih1[2 * HD + j];
  const float hnb1 = hl ? 0.f : bhh1[2 * HD + j];
  const float fb_l = hl ? 0.f : fcb[0];

  // ---- state ----
  float hv1h[6], hv2h[6];                // my k-half of h1_{t-1}, h2_{t-1}
#pragma unroll
  for (int i = 0; i < 6; ++i) { hv1h[i] = 0.f; hv2h[i] = 0.f; }
  float h1 = 0.f, h2 = 0.f;

  const float* xp = x + (size_t)b * Tlen * IND + hl * 9;  // my 9 floats per step
  float* outp = out + (size_t)b * Tlen;

  float xA[9], xB[9];
#pragma unroll
  for (int i = 0; i < 9; ++i) xA[i] = xp[i];

#define STEP(XV, TT)                                                                    \
  do {                                                                                  \
    /* ---- layer 0 partial dots (x half + h1 half) ---- */                             \
    float rp = rb0, zp = zb0, inp = inb0, hnp = hnb0;                                   \
    _Pragma("unroll")                                                                   \
    for (int i = 0; i < 9; ++i) {                                                       \
      rp += XV[i] * wrx[i]; zp += XV[i] * wzx[i]; inp += XV[i] * wnx[i];                \
    }                                                                                   \
    _Pragma("unroll")                                                                   \
    for (int i = 0; i < 6; ++i) {                                                       \
      rp += hv1h[i] * wrh[i]; zp += hv1h[i] * wzh[i]; hnp += hv1h[i] * wnh[i];          \
    }                                                                                   \
    float r0 = rp + __shfl_xor(rp, 16);                                                 \
    float z0 = zp + __shfl_xor(zp, 16);                                                 \
    float in0 = inp + __shfl_xor(inp, 16);                                              \
    float hn0 = hnp + __shfl_xor(hnp, 16);                                              \
    float r = sigmoid_f(r0), z = sigmoid_f(z0);                                         \
    float n = tanh_f(in0 + r * hn0);                                                    \
    h1 = n + z * (h1 - n);                                                              \
    if (hl == 0 && act) sh1[j] = h1;                                                    \
    __builtin_amdgcn_wave_barrier();                                                    \
    /* ---- deferred FC of step TT-1 (uses hv2h = h2_{TT-1}) ---- */                    \
    float op = fb_l;                                                                    \
    _Pragma("unroll")                                                                   \
    for (int i = 0; i < 6; ++i) op += hv2h[i] * fw6[i];                                 \
    float o = op + __shfl_xor(op, 16);                                                  \
    if (TT > 0 && hl == 0 && lane15 == 0) outp[TT - 1] = o;                             \
    /* ---- layer 1 hh partials (h2_{TT-1}, already in regs) ---- */                    \
    float r1p = rb1, z1p = zb1, hn1p = hnb1;                                            \
    _Pragma("unroll")                                                                   \
    for (int i = 0; i < 6; ++i) {                                                       \
      r1p += hv2h[i] * wr1h[i]; z1p += hv2h[i] * wz1h[i]; hn1p += hv2h[i] * wn1h[i];    \
    }                                                                                   \
    /* ---- read back h1_t (write had hh1+fc time to complete) ---- */                  \
    _Pragma("unroll")                                                                   \
    for (int i = 0; i < 6; ++i) hv1h[i] = sh1[hl * 6 + i];                              \
    float in1p = inb1;                                                                  \
    _Pragma("unroll")                                                                   \
    for (int i = 0; i < 6; ++i) {                                                       \
      r1p += hv1h[i] * wr1i[i]; z1p += hv1h[i] * wz1i[i]; in1p += hv1h[i] * wn1i[i];    \
    }                                                                                   \
    float r1t = r1p + __shfl_xor(r1p, 16);                                              \
    float z1t = z1p + __shfl_xor(z1p, 16);                                              \
    float in1 = in1p + __shfl_xor(in1p, 16);                                            \
    float hn1 = hn1p + __shfl_xor(hn1p, 16);                                            \
    float r1 = sigmoid_f(r1t), z1 = sigmoid_f(z1t);                                     \
    float n1 = tanh_f(in1 + r1 * hn1);                                                  \
    h2 = n1 + z1 * (h2 - n1);                                                           \
    if (hl == 0 && act) sh2[j] = h2;                                                    \
    __builtin_amdgcn_wave_barrier();                                                    \
    /* ---- issue h2_t read now; consumed after next step's layer-0 ---- */             \
    _Pragma("unroll")                                                                   \
    for (int i = 0; i < 6; ++i) hv2h[i] = sh2[hl * 6 + i];                              \
  } while (0)

  for (int t = 0; t < Tlen; t += 2) {
    {  // prefetch x for t+1
      const float* p = xp + (size_t)(t + 1) * IND;
#pragma unroll
      for (int i = 0; i < 9; ++i) xB[i] = p[i];
    }
    STEP(xA, t);
    if (t + 2 < Tlen) {  // prefetch x for t+2
      const float* p = xp + (size_t)(t + 2) * IND;
#pragma unroll
      for (int i = 0; i < 9; ++i) xA[i] = p[i];
    }
    STEP(xB, t + 1);
  }
#undef STEP

  // epilogue: FC for t = Tlen-1 (hv2h = h2_{T-1})
  {
    float op = fb_l;
#pragma unroll
    for (int i = 0; i < 6; ++i) op += hv2h[i] * fw6[i];
    float o = op + __shfl_xor(op, 16);
    if (hl == 0 && lane15 == 0) outp[Tlen - 1] = o;
  }
}

extern "C" void kernel_launch(void* const* d_in, const int* in_sizes, int n_in,
                              void* d_out, int out_size, void* d_ws, size_t ws_size,
                              hipStream_t stream) {
  (void)in_sizes; (void)n_in; (void)d_ws; (void)ws_size; (void)out_size;
  const float* x    = (const float*)d_in[0];
  const float* wih0 = (const float*)d_in[1];
  const float* whh0 = (const float*)d_in[2];
  const float* bih0 = (const float*)d_in[3];
  const float* bhh0 = (const float*)d_in[4];
  const float* wih1 = (const float*)d_in[5];
  const float* whh1 = (const float*)d_in[6];
  const float* bih1 = (const float*)d_in[7];
  const float* bhh1 = (const float*)d_in[8];
  const float* fcw  = (const float*)d_in[9];
  const float* fcb  = (const float*)d_in[10];
  float* out = (float*)d_out;

  hipLaunchKernelGGL(gru2_fused32, dim3(Bsz / 8), dim3(256), 0, stream,
                     x, wih0, whh0, bih0, bhh0, wih1, whh1, bih1, bhh1, fcw, fcb, out);
}